// Round 1
// baseline (1027.100 us; speedup 1.0000x reference)
//
#include <hip/hip_runtime.h>

#define B_    128
#define NPOS  64
#define DIN   1024
#define HH    16
#define DH    64
#define E_    1024

typedef __bf16 bf16x8 __attribute__((ext_vector_type(8)));
typedef float  f32x4  __attribute__((ext_vector_type(4)));

union F4 { float4 v; float f[4]; };

__device__ __forceinline__ unsigned int pk2bf(float a, float b) {
    unsigned int ua = __float_as_uint(a);
    unsigned int ub = __float_as_uint(b);
    ua = (ua + 0x7fffu + ((ua >> 16) & 1u)) >> 16;
    ub = (ub + 0x7fffu + ((ub >> 16) & 1u)) >> 16;
    return ua | (ub << 16);
}
__device__ __forceinline__ unsigned short f2bf(float a) {
    unsigned int u = __float_as_uint(a);
    u = (u + 0x7fffu + ((u >> 16) & 1u)) >> 16;
    return (unsigned short)u;
}
__device__ __forceinline__ float bf2f(unsigned int u) {
    return __uint_as_float(u << 16);
}

// ---------------- Kernel 1: grouped projections (q,k,v) ----------------
// per block: C[128 x 128] = A[128 x 1024] * B[1024 x 128] for one position n
// A = in[:, n, :] fp32 -> bf16 ; B = w[n, :, e0:e0+128] fp32 -> bf16 (transposed in LDS)
__global__ __launch_bounds__(256, 2) void proj_kernel(
    const float* __restrict__ qin, const float* __restrict__ kin, const float* __restrict__ vin,
    const float* __restrict__ wq,  const float* __restrict__ wk,  const float* __restrict__ wv,
    unsigned short* __restrict__ qp, unsigned short* __restrict__ kp, unsigned short* __restrict__ vp) {
    const int e0 = blockIdx.x * 128;
    const int n  = blockIdx.y;
    const int z  = blockIdx.z;
    const float* in = (z == 0) ? qin : (z == 1) ? kin : vin;
    const float* w  = (z == 0) ? wq  : (z == 1) ? wk  : wv;
    unsigned short* outp = (z == 0) ? qp : (z == 1) ? kp : vp;

    __shared__ __attribute__((aligned(16))) unsigned short As[128 * 72]; // [m][k]
    __shared__ __attribute__((aligned(16))) unsigned short Bs[128 * 72]; // [e][k] (transposed)

    const int t = threadIdx.x;
    const int lane = t & 63, wave = t >> 6;
    const int wm = wave >> 1, wn = wave & 1;

    f32x4 acc[4][4];
#pragma unroll
    for (int i = 0; i < 4; i++)
#pragma unroll
        for (int j = 0; j < 4; j++) acc[i][j] = (f32x4){0.f, 0.f, 0.f, 0.f};

    const float* inA = in + n * DIN;                       // + m*(NPOS*DIN) + k
    const float* wB  = w + (size_t)n * DIN * E_ + e0;      // + k*E_ + e

    const int afr = t & 15, ar0 = t >> 4;                  // A staging: 16 f4/row
    const int beb = t & 31, bkq = t >> 5;                  // B staging

    for (int kb = 0; kb < DIN; kb += 64) {
        // stage A (128 rows x 64 k)
#pragma unroll
        for (int p = 0; p < 8; p++) {
            int row = ar0 + p * 16;
            F4 v; v.v = *(const float4*)(inA + (size_t)row * (NPOS * DIN) + kb + afr * 4);
            uint2 pk; pk.x = pk2bf(v.f[0], v.f[1]); pk.y = pk2bf(v.f[2], v.f[3]);
            *(uint2*)&As[row * 72 + afr * 4] = pk;
        }
        // stage B transposed: Bs[e][k] <- w[k][e], 4x4 micro-transpose in regs
#pragma unroll
        for (int p = 0; p < 2; p++) {
            int k = (bkq + p * 8) * 4;
            const float* src = wB + (size_t)(kb + k) * E_ + beb * 4;
            F4 c0, c1, c2, c3;
            c0.v = *(const float4*)(src);
            c1.v = *(const float4*)(src + E_);
            c2.v = *(const float4*)(src + 2 * E_);
            c3.v = *(const float4*)(src + 3 * E_);
#pragma unroll
            for (int x = 0; x < 4; x++) {
                uint2 pk; pk.x = pk2bf(c0.f[x], c1.f[x]); pk.y = pk2bf(c2.f[x], c3.f[x]);
                *(uint2*)&Bs[(beb * 4 + x) * 72 + k] = pk;
            }
        }
        __syncthreads();
#pragma unroll
        for (int ks = 0; ks < 64; ks += 32) {
            bf16x8 a[4], b[4];
            const int koff = ks + (lane >> 4) * 8;
#pragma unroll
            for (int i = 0; i < 4; i++)
                a[i] = *(const bf16x8*)&As[(wm * 64 + i * 16 + (lane & 15)) * 72 + koff];
#pragma unroll
            for (int j = 0; j < 4; j++)
                b[j] = *(const bf16x8*)&Bs[(wn * 64 + j * 16 + (lane & 15)) * 72 + koff];
#pragma unroll
            for (int i = 0; i < 4; i++)
#pragma unroll
                for (int j = 0; j < 4; j++)
                    acc[i][j] = __builtin_amdgcn_mfma_f32_16x16x32_bf16(a[i], b[j], acc[i][j], 0, 0, 0);
        }
        __syncthreads();
    }
    // epilogue: C/D map col=lane&15, row=(lane>>4)*4+r  -> bf16 store
    const int col_l = lane & 15, rq = lane >> 4;
#pragma unroll
    for (int i = 0; i < 4; i++)
#pragma unroll
        for (int j = 0; j < 4; j++) {
            int e = e0 + wn * 64 + j * 16 + col_l;
#pragma unroll
            for (int r = 0; r < 4; r++) {
                int m = wm * 64 + i * 16 + rq * 4 + r;
                outp[(size_t)m * (NPOS * E_) + n * E_ + e] = f2bf(acc[i][j][r]);
            }
        }
}

// ---------------- Kernel 2: attention per (b,h) ----------------
__global__ __launch_bounds__(256) void attn_kernel(
    const unsigned short* __restrict__ qp, const unsigned short* __restrict__ kp,
    const unsigned short* __restrict__ vp,
    float* __restrict__ attn_out,            // [B][H][64][64] fp32
    unsigned short* __restrict__ out_ws) {   // bf16 [B][64][H*DH]
    const int bid = blockIdx.x;
    const int b = bid >> 4, h = bid & 15;
    __shared__ __attribute__((aligned(16))) float qs[64 * 68];   // q tile; reused for V
    __shared__ __attribute__((aligned(16))) float kt[64 * 68];   // K transposed [d][j]
    __shared__ __attribute__((aligned(16))) float sc[64 * 68];   // scores / attn
    const int t = threadIdx.x;
    const size_t base = (size_t)b * 64 * E_ + h * DH;

    // stage q and k^T
#pragma unroll
    for (int p = 0; p < 4; p++) {
        int idx = p * 1024 + t * 4;
        int r = idx >> 6, c = idx & 63;
        uint2 q2 = *(const uint2*)(qp + base + r * E_ + c);
        float4 qv = { bf2f(q2.x & 0xffffu), bf2f(q2.x >> 16), bf2f(q2.y & 0xffffu), bf2f(q2.y >> 16) };
        *(float4*)&qs[r * 68 + c] = qv;
        uint2 k2 = *(const uint2*)(kp + base + r * E_ + c);
        kt[(c + 0) * 68 + r] = bf2f(k2.x & 0xffffu);
        kt[(c + 1) * 68 + r] = bf2f(k2.x >> 16);
        kt[(c + 2) * 68 + r] = bf2f(k2.y & 0xffffu);
        kt[(c + 3) * 68 + r] = bf2f(k2.y >> 16);
    }
    __syncthreads();
    const int ti = t >> 4, tj = t & 15;
    const int i0 = ti * 4, j0 = tj * 4;
    float s[4][4] = {};
    for (int k4 = 0; k4 < 64; k4 += 4) {
        F4 qv[4], kv[4];
#pragma unroll
        for (int r = 0; r < 4; r++) qv[r].v = *(const float4*)&qs[(i0 + r) * 68 + k4];
#pragma unroll
        for (int kk = 0; kk < 4; kk++) kv[kk].v = *(const float4*)&kt[(k4 + kk) * 68 + j0];
#pragma unroll
        for (int r = 0; r < 4; r++)
#pragma unroll
            for (int c = 0; c < 4; c++)
#pragma unroll
                for (int kk = 0; kk < 4; kk++)
                    s[r][c] += qv[r].f[kk] * kv[kk].f[c];
    }
#pragma unroll
    for (int r = 0; r < 4; r++)
#pragma unroll
        for (int c = 0; c < 4; c++)
            sc[(i0 + r) * 68 + j0 + c] = s[r][c] * 0.125f;   // 1/sqrt(64)
    __syncthreads();
    // stage V into qs (q no longer needed)
#pragma unroll
    for (int p = 0; p < 4; p++) {
        int idx = p * 1024 + t * 4;
        int r = idx >> 6, c = idx & 63;
        uint2 v2 = *(const uint2*)(vp + base + r * E_ + c);
        float4 vv = { bf2f(v2.x & 0xffffu), bf2f(v2.x >> 16), bf2f(v2.y & 0xffffu), bf2f(v2.y >> 16) };
        *(float4*)&qs[r * 68 + c] = vv;
    }
    // softmax per row
    if (t < 64) {
        float m = -1e30f;
        for (int j = 0; j < 64; j++) m = fmaxf(m, sc[t * 68 + j]);
        float sum = 0.f;
        for (int j = 0; j < 64; j++) {
            float e = __expf(sc[t * 68 + j] - m);
            sc[t * 68 + j] = e; sum += e;
        }
        float inv = 1.f / sum;
        for (int j = 0; j < 64; j++) sc[t * 68 + j] *= inv;
    }
    __syncthreads();
    // write attn (output 1)
    float* abase = attn_out + (size_t)bid * 4096;
#pragma unroll
    for (int p = 0; p < 4; p++) {
        int idx = p * 1024 + t * 4;
        int r = idx >> 6, c = idx & 63;
        float4 av = { sc[r * 68 + c], sc[r * 68 + c + 1], sc[r * 68 + c + 2], sc[r * 68 + c + 3] };
        *(float4*)(abase + idx) = av;
    }
    // PV
    float o[4][4] = {};
    for (int j4 = 0; j4 < 64; j4 += 4) {
        F4 av[4], vv[4];
#pragma unroll
        for (int r = 0; r < 4; r++) av[r].v = *(const float4*)&sc[(i0 + r) * 68 + j4];
#pragma unroll
        for (int jj = 0; jj < 4; jj++) vv[jj].v = *(const float4*)&qs[(j4 + jj) * 68 + j0];
#pragma unroll
        for (int r = 0; r < 4; r++)
#pragma unroll
            for (int c = 0; c < 4; c++)
#pragma unroll
                for (int jj = 0; jj < 4; jj++)
                    o[r][c] += av[r].f[jj] * vv[jj].f[c];
    }
#pragma unroll
    for (int r = 0; r < 4; r++) {
        uint2 pk; pk.x = pk2bf(o[r][0], o[r][1]); pk.y = pk2bf(o[r][2], o[r][3]);
        *(uint2*)(out_ws + (size_t)(b * 64 + i0 + r) * E_ + h * DH + j0) = pk;
    }
}

// ---------------- Kernel 3: fused fc + gate + activation ----------------
// C_fc[m,n] = sum_k out[m,k]*fc_w[n,k] ; C_g likewise ; out = sigmoid(g+gb)*tanh(f+fb)
__global__ __launch_bounds__(256, 2) void fcgate_kernel(
    const unsigned short* __restrict__ a,   // bf16 [8192][1024]
    const float* __restrict__ fcw, const float* __restrict__ fcb,
    const float* __restrict__ gw,  const float* __restrict__ gb,
    float* __restrict__ outp) {             // fp32 [8192][1024]
    const int n0 = blockIdx.x * 128;
    const int m0 = blockIdx.y * 128;
    __shared__ __attribute__((aligned(16))) unsigned short As[128 * 72];
    __shared__ __attribute__((aligned(16))) unsigned short Bf[128 * 72];
    __shared__ __attribute__((aligned(16))) unsigned short Bg[128 * 72];
    const int t = threadIdx.x;
    const int lane = t & 63, wave = t >> 6;
    const int wm = wave >> 1, wn = wave & 1;

    f32x4 accf[4][4], accg[4][4];
#pragma unroll
    for (int i = 0; i < 4; i++)
#pragma unroll
        for (int j = 0; j < 4; j++) {
            accf[i][j] = (f32x4){0.f, 0.f, 0.f, 0.f};
            accg[i][j] = (f32x4){0.f, 0.f, 0.f, 0.f};
        }

    const int afr = t & 7,  ar0 = t >> 3;   // A: 8 x 16B chunks per row
    const int bfr = t & 15, br0 = t >> 4;   // B: 16 x float4 per row

    for (int kb = 0; kb < 1024; kb += 64) {
#pragma unroll
        for (int p = 0; p < 4; p++) {
            int row = ar0 + p * 32;
            *(uint4*)&As[row * 72 + afr * 8] =
                *(const uint4*)(a + (size_t)(m0 + row) * 1024 + kb + afr * 8);
        }
#pragma unroll
        for (int p = 0; p < 8; p++) {
            int row = br0 + p * 16;
            F4 cf; cf.v = *(const float4*)(fcw + (size_t)(n0 + row) * 1024 + kb + bfr * 4);
            uint2 pkf; pkf.x = pk2bf(cf.f[0], cf.f[1]); pkf.y = pk2bf(cf.f[2], cf.f[3]);
            *(uint2*)&Bf[row * 72 + bfr * 4] = pkf;
            F4 cg; cg.v = *(const float4*)(gw + (size_t)(n0 + row) * 1024 + kb + bfr * 4);
            uint2 pkg; pkg.x = pk2bf(cg.f[0], cg.f[1]); pkg.y = pk2bf(cg.f[2], cg.f[3]);
            *(uint2*)&Bg[row * 72 + bfr * 4] = pkg;
        }
        __syncthreads();
#pragma unroll
        for (int ks = 0; ks < 64; ks += 32) {
            bf16x8 av[4], bfv[4], bgv[4];
            const int koff = ks + (lane >> 4) * 8;
#pragma unroll
            for (int i = 0; i < 4; i++)
                av[i] = *(const bf16x8*)&As[(wm * 64 + i * 16 + (lane & 15)) * 72 + koff];
#pragma unroll
            for (int j = 0; j < 4; j++) {
                bfv[j] = *(const bf16x8*)&Bf[(wn * 64 + j * 16 + (lane & 15)) * 72 + koff];
                bgv[j] = *(const bf16x8*)&Bg[(wn * 64 + j * 16 + (lane & 15)) * 72 + koff];
            }
#pragma unroll
            for (int i = 0; i < 4; i++)
#pragma unroll
                for (int j = 0; j < 4; j++) {
                    accf[i][j] = __builtin_amdgcn_mfma_f32_16x16x32_bf16(av[i], bfv[j], accf[i][j], 0, 0, 0);
                    accg[i][j] = __builtin_amdgcn_mfma_f32_16x16x32_bf16(av[i], bgv[j], accg[i][j], 0, 0, 0);
                }
        }
        __syncthreads();
    }
    const int col_l = lane & 15, rq = lane >> 4;
#pragma unroll
    for (int i = 0; i < 4; i++)
#pragma unroll
        for (int j = 0; j < 4; j++) {
            int col = n0 + wn * 64 + j * 16 + col_l;
            float bfb = fcb[col], bgb = gb[col];
#pragma unroll
            for (int r = 0; r < 4; r++) {
                int m = m0 + wm * 64 + i * 16 + rq * 4 + r;
                float f = accf[i][j][r] + bfb;
                float g = accg[i][j][r] + bgb;
                float ef = __expf(2.f * f);
                float th = (ef - 1.f) / (ef + 1.f);      // tanh(f)
                float sg = 1.f / (1.f + __expf(-g));     // sigmoid(g)
                outp[(size_t)m * 1024 + col] = sg * th;
            }
        }
}

extern "C" void kernel_launch(void* const* d_in, const int* in_sizes, int n_in,
                              void* d_out, int out_size, void* d_ws, size_t ws_size,
                              hipStream_t stream) {
    const float* q      = (const float*)d_in[0];
    const float* k      = (const float*)d_in[1];
    const float* v      = (const float*)d_in[2];
    const float* w_q    = (const float*)d_in[3];
    const float* w_k    = (const float*)d_in[4];
    const float* w_v    = (const float*)d_in[5];
    const float* fc_w   = (const float*)d_in[6];
    const float* fc_b   = (const float*)d_in[7];
    const float* gate_w = (const float*)d_in[8];
    const float* gate_b = (const float*)d_in[9];

    float* out  = (float*)d_out;              // [128*64][1024]
    float* attn = out + 8388608;              // [128][16][64][64]

    unsigned short* qp  = (unsigned short*)d_ws;   // bf16 [128][64][1024] each
    unsigned short* kp  = qp + 8388608;
    unsigned short* vp  = kp + 8388608;
    unsigned short* ows = vp + 8388608;            // bf16 [8192][1024]

    dim3 blk(256);
    proj_kernel<<<dim3(8, 64, 3), blk, 0, stream>>>(q, k, v, w_q, w_k, w_v, qp, kp, vp);
    attn_kernel<<<dim3(2048), blk, 0, stream>>>(qp, kp, vp, attn, ows);
    fcgate_kernel<<<dim3(8, 64), blk, 0, stream>>>(ows, fc_w, fc_b, gate_w, gate_b, out);
}